// Round 9
// baseline (785.221 us; speedup 1.0000x reference)
//
#include <hip/hip_runtime.h>
#include <stdint.h>

typedef unsigned short u16;
typedef float f32x4 __attribute__((ext_vector_type(4)));
typedef unsigned int u32x4 __attribute__((ext_vector_type(4)));
typedef _Float16 f16x8 __attribute__((ext_vector_type(8)));

#define PLANE (1024u * 1024u)
#define NFREQ 17

// cos(2*pi*j/32); sin(2*pi*j/32) = COS32[(j+24)&31]
__device__ constexpr float COS32[32] = {
    1.0f,         0.98078528f,  0.92387953f,  0.83146961f,
    0.70710678f,  0.55557023f,  0.38268343f,  0.19509032f,
    0.0f,        -0.19509032f, -0.38268343f, -0.55557023f,
   -0.70710678f, -0.83146961f, -0.92387953f, -0.98078528f,
   -1.0f,        -0.98078528f, -0.92387953f, -0.83146961f,
   -0.70710678f, -0.55557023f, -0.38268343f, -0.19509032f,
    0.0f,         0.19509032f,  0.38268343f,  0.55557023f,
    0.70710678f,  0.83146961f,  0.92387953f,  0.98078528f
};

// DFT along tube axis t (len 32), frequencies 0..16, fp32 in -> fp16 re/im out.
// out layout: [2][17][PLANE]  (re planes 0..16, im planes 17..33)
__global__ __launch_bounds__(256) void dft32(const float* __restrict__ in,
                                             _Float16* __restrict__ out) {
  size_t i = (size_t)blockIdx.x * 256 + threadIdx.x;  // < PLANE
  float xs[32];
#pragma unroll
  for (int t = 0; t < 32; ++t) xs[t] = in[(size_t)t * PLANE + i];
#pragma unroll
  for (int k = 0; k <= 16; ++k) {
    float re = 0.f, im = 0.f;
#pragma unroll
    for (int t = 0; t < 32; ++t) {
      int j = (k * t) & 31;
      re += xs[t] * COS32[j];
      im -= xs[t] * COS32[(j + 24) & 31];
    }
    out[(size_t)k * PLANE + i] = (_Float16)re;
    out[(size_t)(NFREQ + k) * PLANE + i] = (_Float16)im;
  }
}

// 1024x1024 16-bit plane transpose (bit-preserving), grid.z = 34 planes
__global__ __launch_bounds__(256) void tr1024(const u16* __restrict__ src,
                                              u16* __restrict__ dst) {
  const int z = blockIdx.z;
  const u16* s = src + (size_t)z * PLANE;
  u16* d = dst + (size_t)z * PLANE;
  __shared__ u16 tile[64][80];  // pad 80 el = 160B rows, conflict-light
  const int r0 = blockIdx.y * 64, c0 = blockIdx.x * 64;
  const int tid = threadIdx.x;
#pragma unroll
  for (int i = 0; i < 2; ++i) {
    int v = tid + i * 256;
    int row = v >> 3, c8 = (v & 7) * 8;
    *(u32x4*)&tile[row][c8] = *(const u32x4*)&s[(size_t)(r0 + row) * 1024 + c0 + c8];
  }
  __syncthreads();
#pragma unroll
  for (int i = 0; i < 2; ++i) {
    int v = tid + i * 256;
    int c = v >> 3, r8 = (v & 7) * 8;
    u16 tmp[8] __attribute__((aligned(16)));
#pragma unroll
    for (int j = 0; j < 8; ++j) tmp[j] = tile[r8 + j][c];
    *(u32x4*)&d[(size_t)(c0 + c) * 1024 + r0 + r8] = *(const u32x4*)tmp;
  }
}

#define BK 32
#define LDSS 40  // 32 + 8 pad (f16 elements): row stride 80B, 16B-aligned reads

// Per-frequency complex GEMM: Cf[k] = Wf[k](p,q) * Xf[k](q,m), m-chunk [m0, m0+CW)
// wf:  [2][17][PLANE] f16, row-major (p, q)
// xfT: [2][17][PLANE] f16, row-major (m, q)   (transposed Xf)
// cf:  [2][17][1024*CW] fp32 (re block then im block), row-major (p, m_local)
__global__ __launch_bounds__(256) void cgemm17(const _Float16* __restrict__ wf,
                                               const _Float16* __restrict__ xfT,
                                               float* __restrict__ cf,
                                               int m0, int CW) {
  const int kf = blockIdx.z;
  const _Float16* Are = wf + (size_t)kf * PLANE;
  const _Float16* Aim = wf + (size_t)(NFREQ + kf) * PLANE;
  const _Float16* Bre = xfT + (size_t)kf * PLANE;
  const _Float16* Bim = xfT + (size_t)(NFREQ + kf) * PLANE;

  const int ptile = blockIdx.y * 128;
  const int mtile = blockIdx.x * 128;  // within chunk
  const int mg = m0 + mtile;           // global m row in xfT

  __shared__ u16 sAre[128 * LDSS], sAim[128 * LDSS];
  __shared__ u16 sBre[128 * LDSS], sBim[128 * LDSS];

  const int tid = threadIdx.x;
  const int lane = tid & 63;
  const int wid = tid >> 6;
  const int wm = wid >> 1;  // 2x2 wave grid, each wave owns 64x64
  const int wn = wid & 1;
  const int lr = lane & 15;
  const int lk = lane >> 4;

  f32x4 accre[4][4] = {};
  f32x4 accim[4][4] = {};

  for (int kk = 0; kk < 1024; kk += BK) {
    __syncthreads();
#pragma unroll
    for (int i = 0; i < 2; ++i) {
      int v = tid + i * 256;        // 0..511
      int row = v >> 2;             // 0..127
      int c8 = (v & 3) * 8;         // 0,8,16,24
      size_t gA = (size_t)(ptile + row) * 1024 + kk + c8;
      size_t gB = (size_t)(mg + row) * 1024 + kk + c8;
      int lo = row * LDSS + c8;
      *(u32x4*)&sAre[lo] = *(const u32x4*)&Are[gA];
      *(u32x4*)&sAim[lo] = *(const u32x4*)&Aim[gA];
      *(u32x4*)&sBre[lo] = *(const u32x4*)&Bre[gB];
      *(u32x4*)&sBim[lo] = *(const u32x4*)&Bim[gB];
    }
    __syncthreads();

    f16x8 are[4], aim[4], nim[4], bre[4], bim[4];
#pragma unroll
    for (int mi = 0; mi < 4; ++mi) {
      int r = (wm * 64 + mi * 16 + lr) * LDSS + lk * 8;
      are[mi] = *(const f16x8*)&sAre[r];
      aim[mi] = *(const f16x8*)&sAim[r];
      nim[mi] = -aim[mi];  // negated im operand (compiler-managed, hazard-safe)
    }
#pragma unroll
    for (int ni = 0; ni < 4; ++ni) {
      int r = (wn * 64 + ni * 16 + lr) * LDSS + lk * 8;
      bre[ni] = *(const f16x8*)&sBre[r];
      bim[ni] = *(const f16x8*)&sBim[r];
    }
#pragma unroll
    for (int mi = 0; mi < 4; ++mi)
#pragma unroll
      for (int ni = 0; ni < 4; ++ni) {
        // (Wre + i Wim)(Xre + i Xim): re = WreXre - WimXim, im = WreXim + WimXre
        accre[mi][ni] = __builtin_amdgcn_mfma_f32_16x16x32_f16(are[mi], bre[ni], accre[mi][ni], 0, 0, 0);
        accim[mi][ni] = __builtin_amdgcn_mfma_f32_16x16x32_f16(are[mi], bim[ni], accim[mi][ni], 0, 0, 0);
        accre[mi][ni] = __builtin_amdgcn_mfma_f32_16x16x32_f16(nim[mi], bim[ni], accre[mi][ni], 0, 0, 0);
        accim[mi][ni] = __builtin_amdgcn_mfma_f32_16x16x32_f16(aim[mi], bre[ni], accim[mi][ni], 0, 0, 0);
      }
  }

  float* cre = cf;
  float* cim = cf + (size_t)NFREQ * 1024 * CW;
  const size_t pl = (size_t)kf * 1024 * CW;
#pragma unroll
  for (int mi = 0; mi < 4; ++mi)
#pragma unroll
    for (int ni = 0; ni < 4; ++ni)
#pragma unroll
      for (int j = 0; j < 4; ++j) {
        int p = ptile + wm * 64 + mi * 16 + lk * 4 + j;  // D row = (lane>>4)*4+j
        int m = mtile + wn * 64 + ni * 16 + lr;          // D col = lane&15
        cre[pl + (size_t)p * CW + m] = accre[mi][ni][j];
        cim[pl + (size_t)p * CW + m] = accim[mi][ni][j];
      }
}

// inverse DFT (real part) + bias for one m-chunk
__global__ __launch_bounds__(256) void ifft_bias(const float* __restrict__ cf,
                                                 const float* __restrict__ bias,
                                                 float* __restrict__ out,
                                                 int m0, int cwShift) {
  const int CW = 1 << cwShift;
  size_t idx = (size_t)blockIdx.x * 256 + threadIdx.x;  // < 1024*CW
  int p = (int)(idx >> cwShift);
  int m = (int)(idx & (CW - 1));

  const float* cre = cf;
  const float* cim = cf + (size_t)NFREQ * 1024 * CW;

  float re[17], im[16];
#pragma unroll
  for (int k = 0; k <= 16; ++k) re[k] = cre[(size_t)k * 1024 * CW + idx];
#pragma unroll
  for (int k = 1; k <= 15; ++k) im[k] = cim[(size_t)k * 1024 * CW + idx];

  const float b = bias[(size_t)p * 1024 + m0 + m];
  const size_t ob = (size_t)p * 1024 + m0 + m;

#pragma unroll
  for (int t = 0; t < 32; ++t) {
    float acc = re[0] + ((t & 1) ? -re[16] : re[16]);
#pragma unroll
    for (int k = 1; k <= 15; ++k) {
      int j = (k * t) & 31;
      acc += 2.0f * (re[k] * COS32[j] - im[k] * COS32[(j + 24) & 31]);
    }
    out[(size_t)t * PLANE + ob] = acc * 0.03125f + b;
  }
}

extern "C" void kernel_launch(void* const* d_in, const int* in_sizes, int n_in,
                              void* d_out, int out_size, void* d_ws, size_t ws_size,
                              hipStream_t stream) {
  const float* x = (const float*)d_in[0];     // (32, 1024, 1024)  [t][q][m]
  const float* w = (const float*)d_in[1];     // (32, 1024, 1024)  [t][p][q]
  const float* bias = (const float*)d_in[2];  // (1, 1024, 1024)   [p][m]
  float* out = (float*)d_out;                 // (32, 1024, 1024)  [t][p][m]

  char* ws = (char*)d_ws;
  const size_t SEG = (size_t)2 * NFREQ * PLANE * sizeof(u16);  // 68 MiB
  _Float16* wfb = (_Float16*)ws;           // Wf f16 [2][17][p][q]
  _Float16* xfT = (_Float16*)(ws + SEG);   // XfT f16 [2][17][m][q]
  float* cf = (float*)(ws + 2 * SEG);      // Cf fp32 chunk [2][17][1024][CW]
  // Xf natural layout is staged in d_out (dead before ifft writes begin)
  _Float16* xfN = (_Float16*)d_out;

  // adaptive Cf chunk width based on available workspace
  int cwShift = 9;  // CW=512
  while (cwShift > 7 &&
         2 * SEG + (size_t)2 * NFREQ * 1024 * (1u << cwShift) * 4 > ws_size)
    --cwShift;
  const int CW = 1 << cwShift;
  const int nchunks = 1024 / CW;

  dft32<<<4096, 256, 0, stream>>>(w, wfb);
  dft32<<<4096, 256, 0, stream>>>(x, xfN);
  tr1024<<<dim3(16, 16, 34), 256, 0, stream>>>((const u16*)xfN, (u16*)xfT);

  for (int c = 0; c < nchunks; ++c) {
    int m0 = c * CW;
    cgemm17<<<dim3(CW / 128, 8, NFREQ), 256, 0, stream>>>(wfb, xfT, cf, m0, CW);
    ifft_bias<<<(1024 * CW) / 256, 256, 0, stream>>>(cf, bias, out, m0, cwShift);
  }
}